// Round 9
// baseline (292.521 us; speedup 1.0000x reference)
//
#include <hip/hip_runtime.h>
#include <hip/hip_bf16.h>

#define N_SIDE 14
#define N_PATCH (N_SIDE * N_SIDE)   // 196
#define D_BB 384
#define DQ_BB (D_BB / 4)             // 96 float4 per cell
#define D_MODEL 512
#define CQ (D_MODEL / 4)             // 128 col-quads
#define BT_TOTAL 2048
#define LN_EPS 1e-5f
#define ROWS 8                       // rows per gemm block
#define KP 4                         // K partitions per gemm block
#define KCHUNK (D_BB / KP)           // 96
#define GROUPS 4                     // cell groups per pool sub-block
#define SPLIT 2                      // pool sub-blocks per bt (disjoint outputs)
#define ESTRIDE (GROUPS * SPLIT)     // 8 effective groups

// ---- instrumentation: repeat the pool sweep; iter 0 is the real one ----
#define ITERS 24
#define SHIFT_STEP 15                // gcd(15,196)=1 -> distinct cell windows

__device__ __forceinline__ void fma4(float4& a, float s, const float4& wv) {
    a.x = fmaf(s, wv.x, a.x);
    a.y = fmaf(s, wv.y, a.y);
    a.z = fmaf(s, wv.z, a.z);
    a.w = fmaf(s, wv.w, a.w);
}

__device__ __forceinline__ void add4(float4& a, const float4& b) {
    a.x += b.x; a.y += b.y; a.z += b.z; a.w += b.w;
}

__device__ __forceinline__ void box_params(const float* __restrict__ bboxes, int bt,
                                           int& x1, int& y1, int& wd, int& total) {
    const float bx1 = bboxes[bt * 4 + 0];
    const float by1 = bboxes[bt * 4 + 1];
    const float bx2 = bboxes[bt * 4 + 2];
    const float by2 = bboxes[bt * 4 + 3];
    // match reference exactly: clip -> trunc/ceil -> clip -> max
    x1 = (int)fminf(fmaxf(bx1 * (float)N_SIDE, 0.f), (float)(N_SIDE - 1));
    y1 = (int)fminf(fmaxf(by1 * (float)N_SIDE, 0.f), (float)(N_SIDE - 1));
    int x2 = (int)fminf(fmaxf(ceilf(fminf(fmaxf(bx2 * (float)N_SIDE, 0.f), (float)N_SIDE)), 1.f), (float)N_SIDE);
    int y2 = (int)fminf(fmaxf(ceilf(fminf(fmaxf(by2 * (float)N_SIDE, 0.f), (float)N_SIDE)), 1.f), (float)N_SIDE);
    x2 = max(x2, x1 + 1);
    y2 = max(y2, y1 + 1);
    wd = x2 - x1;
    total = wd * (y2 - y1);
}

// ---------------- Kernel 1: ROI pool partial sums (R6 structure, x ITERS sweeps) ----------------
// grid = BT_TOTAL*SPLIT, block = 384 = 96 quads x 4 cell-groups.
__global__ __launch_bounds__(384) void pool_kernel(
    const float* __restrict__ patch,   // [BT,196,384]
    const float* __restrict__ bboxes,  // [BT,4]
    float* __restrict__ pooled,        // [SPLIT,BT,384] raw partial sums (iter 0)
    float* __restrict__ dummy)         // [SPLIT*BT,384] sink for iters 1..ITERS-1
{
    const int bid = blockIdx.x;
    const int bt  = bid >> 1;
    const int s   = bid & 1;
    const int t   = threadIdx.x;
    const int qd  = t % DQ_BB;              // channel quad 0..95
    const int g   = t / DQ_BB;              // cell group 0..3
    const int e   = s * GROUPS + g;         // effective group 0..7

    int x1, y1, wd, total;
    box_params(bboxes, bt, x1, y1, wd, total);
    const float inv_wd = 1.f / (float)wd;
    const int cell0 = y1 * N_SIDE + x1;

    const float4* __restrict__ base = (const float4*)patch + (size_t)bt * N_PATCH * DQ_BB + qd;

    // flattened cell c -> grid offset, rotated by shift cells within the bt row
    auto cell_off = [&](int c, int shift) -> size_t {
        const int y = (int)(((float)c + 0.5f) * inv_wd);
        const int x = c - y * wd;
        int gc = cell0 + y * N_SIDE + x + shift;
        if (gc >= N_PATCH) gc -= N_PATCH;   // cell0+y*14+x <= 195, shift <= 195
        return (size_t)gc * DQ_BB;
    };

    float4 acc  = make_float4(0.f, 0.f, 0.f, 0.f);   // real (iter 0)
    float4 accd = make_float4(0.f, 0.f, 0.f, 0.f);   // dummy (iters 1+)

    for (int it = 0; it < ITERS; ++it) {
        const int shift = (SHIFT_STEP * it) % N_PATCH;   // 0 for it==0
        float4 a = make_float4(0.f, 0.f, 0.f, 0.f);
        int c = e;
        for (; c + 3 * ESTRIDE < total; c += 4 * ESTRIDE) {
            const float4 v0 = base[cell_off(c, shift)];
            const float4 v1 = base[cell_off(c + ESTRIDE, shift)];
            const float4 v2 = base[cell_off(c + 2 * ESTRIDE, shift)];
            const float4 v3 = base[cell_off(c + 3 * ESTRIDE, shift)];
            a.x += (v0.x + v1.x) + (v2.x + v3.x);
            a.y += (v0.y + v1.y) + (v2.y + v3.y);
            a.z += (v0.z + v1.z) + (v2.z + v3.z);
            a.w += (v0.w + v1.w) + (v2.w + v3.w);
        }
        for (; c < total; c += ESTRIDE) {
            const float4 v = base[cell_off(c, shift)];
            a.x += v.x; a.y += v.y; a.z += v.z; a.w += v.w;
        }
        if (it == 0) add4(acc, a);
        else         add4(accd, a);
    }

    // dummy sink: one float per thread, keeps iters 1+ loads alive
    dummy[(size_t)bid * 384 + t] = accd.x + accd.y + accd.z + accd.w;

    __shared__ float4 part[GROUPS][DQ_BB];   // 6 KB
    part[g][qd] = acc;
    __syncthreads();

    if (t < DQ_BB) {
        float4 sm = part[0][t];
#pragma unroll
        for (int p = 1; p < GROUPS; ++p) add4(sm, part[p][t]);
        ((float4*)pooled)[((size_t)s * BT_TOTAL + bt) * DQ_BB + t] = sm;
    }
}

// ---------------- Kernel 2: GEMM (sums @ W)/count + b + LayerNorm + vis blend (R6 unchanged) ----------------
// grid = BT_TOTAL/ROWS = 256, block = 512 = 128 col-quads x 4 K-partitions
__global__ __launch_bounds__(512) void gemm_ln_kernel(
    const float* __restrict__ pooled,    // [SPLIT,BT,384] raw partial sums
    const float* __restrict__ bboxes,    // [BT,4]
    const float* __restrict__ W,         // [384,512]
    const float* __restrict__ bias,      // [512]
    const float* __restrict__ gamma,     // [512]
    const float* __restrict__ beta,      // [512]
    const float* __restrict__ mask_tok,  // [512]
    const float* __restrict__ vis,       // [BT]
    float* __restrict__ out)             // [BT,512]
{
    const int tid  = threadIdx.x;
    const int part = tid >> 7;       // 0..3 (K partition)
    const int jq   = tid & 127;      // col quad 0..127
    const int r0   = blockIdx.x * ROWS;

    __shared__ float sp[ROWS][D_BB];            // 12 KB: the 8 summed rows
    __shared__ float red[KP - 1][32][CQ];       // 48 KB, element-major: conflict-free
    __shared__ float lnred[2][ROWS][2];
    __shared__ float s_invc[ROWS];

    // ---- stage pooled rows into LDS, summing the two split halves ----
    {
        const float4* pa = (const float4*)pooled + (size_t)r0 * DQ_BB;
        const float4* pb = (const float4*)pooled + ((size_t)BT_TOTAL + r0) * DQ_BB;
        float4* sp4 = (float4*)sp;
        for (int i = tid; i < ROWS * DQ_BB; i += 512) {
            float4 a = pa[i];
            add4(a, pb[i]);
            sp4[i] = a;
        }
    }
    if (tid < ROWS) {
        int x1, y1, wd, total;
        box_params(bboxes, r0 + tid, x1, y1, wd, total);
        s_invc[tid] = 1.f / (float)total;
    }
    __syncthreads();

    const float4* Wq = (const float4*)W;   // [384][128] float4
    float4 acc[ROWS];
#pragma unroll
    for (int r = 0; r < ROWS; ++r) acc[r] = make_float4(0.f, 0.f, 0.f, 0.f);

    const int dbase = part * KCHUNK;
#pragma unroll 2
    for (int i = 0; i < KCHUNK / 4; ++i) {
        const int d = dbase + i * 4;
        const float4 w0 = Wq[(size_t)(d + 0) * CQ + jq];
        const float4 w1 = Wq[(size_t)(d + 1) * CQ + jq];
        const float4 w2 = Wq[(size_t)(d + 2) * CQ + jq];
        const float4 w3 = Wq[(size_t)(d + 3) * CQ + jq];
#pragma unroll
        for (int r = 0; r < ROWS; ++r) {
            const float4 a = *(const float4*)&sp[r][d];   // LDS broadcast
            fma4(acc[r], a.x, w0);
            fma4(acc[r], a.y, w1);
            fma4(acc[r], a.z, w2);
            fma4(acc[r], a.w, w3);
        }
    }

    // ---- cross-partition reduction via LDS ----
    if (part != 0) {
#pragma unroll
        for (int r = 0; r < ROWS; ++r) {
            red[part - 1][r * 4 + 0][jq] = acc[r].x;
            red[part - 1][r * 4 + 1][jq] = acc[r].y;
            red[part - 1][r * 4 + 2][jq] = acc[r].z;
            red[part - 1][r * 4 + 3][jq] = acc[r].w;
        }
    }
    __syncthreads();

    if (part == 0) {
#pragma unroll
        for (int p = 0; p < KP - 1; ++p) {
#pragma unroll
            for (int r = 0; r < ROWS; ++r) {
                acc[r].x += red[p][r * 4 + 0][jq];
                acc[r].y += red[p][r * 4 + 1][jq];
                acc[r].z += red[p][r * 4 + 2][jq];
                acc[r].w += red[p][r * 4 + 3][jq];
            }
        }
        const float4 bj = ((const float4*)bias)[jq];
#pragma unroll
        for (int r = 0; r < ROWS; ++r) {
            const float ic = s_invc[r];
            acc[r].x = fmaf(acc[r].x, ic, bj.x);
            acc[r].y = fmaf(acc[r].y, ic, bj.y);
            acc[r].z = fmaf(acc[r].z, ic, bj.z);
            acc[r].w = fmaf(acc[r].w, ic, bj.w);
        }

        // ---- LN partial sums across 128 threads (2 waves) ----
        const int lane = tid & 63;
        const int wv   = tid >> 6;   // 0 or 1
#pragma unroll
        for (int r = 0; r < ROWS; ++r) {
            float s  = acc[r].x + acc[r].y + acc[r].z + acc[r].w;
            float s2 = acc[r].x * acc[r].x + acc[r].y * acc[r].y +
                       acc[r].z * acc[r].z + acc[r].w * acc[r].w;
#pragma unroll
            for (int off = 32; off >= 1; off >>= 1) {
                s  += __shfl_xor(s,  off);
                s2 += __shfl_xor(s2, off);
            }
            if (lane == 0) { lnred[wv][r][0] = s; lnred[wv][r][1] = s2; }
        }
    }
    __syncthreads();

    if (part == 0) {
        const float4 g4 = ((const float4*)gamma)[jq];
        const float4 b4 = ((const float4*)beta)[jq];
        const float4 m4 = ((const float4*)mask_tok)[jq];
#pragma unroll
        for (int r = 0; r < ROWS; ++r) {
            const float s    = lnred[0][r][0] + lnred[1][r][0];
            const float s2   = lnred[0][r][1] + lnred[1][r][1];
            const float mean = s * (1.f / (float)D_MODEL);
            const float var  = s2 * (1.f / (float)D_MODEL) - mean * mean;
            const float rstd = rsqrtf(var + LN_EPS);
            const float v    = vis[r0 + r];
            const float iv   = 1.f - v;
            float4 o;
            o.x = v * ((acc[r].x - mean) * rstd * g4.x + b4.x) + iv * m4.x;
            o.y = v * ((acc[r].y - mean) * rstd * g4.y + b4.y) + iv * m4.y;
            o.z = v * ((acc[r].z - mean) * rstd * g4.z + b4.z) + iv * m4.z;
            o.w = v * ((acc[r].w - mean) * rstd * g4.w + b4.w) + iv * m4.w;
            ((float4*)out)[(size_t)(r0 + r) * CQ + jq] = o;
        }
    }
}

extern "C" void kernel_launch(void* const* d_in, const int* in_sizes, int n_in,
                              void* d_out, int out_size, void* d_ws, size_t ws_size,
                              hipStream_t stream) {
    const float* patch  = (const float*)d_in[0];  // [2048,196,384]
    const float* bboxes = (const float*)d_in[1];  // [2048,4]
    const float* vis    = (const float*)d_in[2];  // [2048]
    // d_in[3] = B, d_in[4] = T (scalars, unused)
    const float* W      = (const float*)d_in[5];  // [384,512]
    const float* bias   = (const float*)d_in[6];  // [512]
    const float* gamma  = (const float*)d_in[7];  // [512]
    const float* beta   = (const float*)d_in[8];  // [512]
    const float* mtok   = (const float*)d_in[9];  // [1,512]

    float* pooled = (float*)d_ws;                               // 6 MB real sums
    float* dummy  = (float*)((char*)d_ws + 8u * 1024 * 1024);   // 6.3 MB sink
    float* out    = (float*)d_out;

    pool_kernel<<<BT_TOTAL * SPLIT, 384, 0, stream>>>(patch, bboxes, pooled, dummy);
    gemm_ln_kernel<<<BT_TOTAL / ROWS, 512, 0, stream>>>(
        pooled, bboxes, W, bias, gamma, beta, mtok, vis, out);
}

// Round 10
// 233.701 us; speedup vs baseline: 1.2517x; 1.2517x over previous
//
#include <hip/hip_runtime.h>
#include <hip/hip_bf16.h>

#define N_SIDE 14
#define N_PATCH (N_SIDE * N_SIDE)   // 196
#define D_BB 384
#define DQ_BB (D_BB / 4)             // 96 float4 per cell
#define D_MODEL 512
#define CQ (D_MODEL / 4)             // 128 col-quads
#define BT_TOTAL 2048
#define LN_EPS 1e-5f
#define PGROUPS 8                    // pool cell groups (768 threads)

#define GROWS 8                      // rows per gemm block
#define GKP 8                        // K partitions (1 wave each)
#define GKCHUNK (D_BB / GKP)         // 48

#define REPEAT 16                    // gemm K-loop instrumentation factor

__device__ __forceinline__ void fma4(float4& a, float s, const float4& wv) {
    a.x = fmaf(s, wv.x, a.x);
    a.y = fmaf(s, wv.y, a.y);
    a.z = fmaf(s, wv.z, a.z);
    a.w = fmaf(s, wv.w, a.w);
}

__device__ __forceinline__ void add4(float4& a, const float4& b) {
    a.x += b.x; a.y += b.y; a.z += b.z; a.w += b.w;
}

__device__ __forceinline__ void box_params(const float* __restrict__ bboxes, int bt,
                                           int& x1, int& y1, int& wd, int& total) {
    const float bx1 = bboxes[bt * 4 + 0];
    const float by1 = bboxes[bt * 4 + 1];
    const float bx2 = bboxes[bt * 4 + 2];
    const float by2 = bboxes[bt * 4 + 3];
    // match reference exactly: clip -> trunc/ceil -> clip -> max
    x1 = (int)fminf(fmaxf(bx1 * (float)N_SIDE, 0.f), (float)(N_SIDE - 1));
    y1 = (int)fminf(fmaxf(by1 * (float)N_SIDE, 0.f), (float)(N_SIDE - 1));
    int x2 = (int)fminf(fmaxf(ceilf(fminf(fmaxf(bx2 * (float)N_SIDE, 0.f), (float)N_SIDE)), 1.f), (float)N_SIDE);
    int y2 = (int)fminf(fmaxf(ceilf(fminf(fmaxf(by2 * (float)N_SIDE, 0.f), (float)N_SIDE)), 1.f), (float)N_SIDE);
    x2 = max(x2, x1 + 1);
    y2 = max(y2, y1 + 1);
    wd = x2 - x1;
    total = wd * (y2 - y1);
}

// ---------------- Kernel 1: ROI mean pool (R4 form: 768 thr, 8 groups, 4-deep) ----------------
__global__ __launch_bounds__(768) void pool_kernel(
    const float* __restrict__ patch,   // [BT,196,384]
    const float* __restrict__ bboxes,  // [BT,4]
    float* __restrict__ pooled)        // [BT,384] means
{
    const int bt = blockIdx.x;
    const int t  = threadIdx.x;
    const int qd = t % DQ_BB;   // channel quad 0..95
    const int g  = t / DQ_BB;   // cell group 0..7

    int x1, y1, wd, total;
    box_params(bboxes, bt, x1, y1, wd, total);
    const float inv_count = 1.f / (float)total;
    const float inv_wd = 1.f / (float)wd;
    const int cell0 = y1 * N_SIDE + x1;

    const float4* __restrict__ base = (const float4*)patch + (size_t)bt * N_PATCH * DQ_BB + qd;

    auto cell_off = [&](int c) -> size_t {
        const int y = (int)(((float)c + 0.5f) * inv_wd);
        const int x = c - y * wd;
        return (size_t)(cell0 + y * N_SIDE + x) * DQ_BB;
    };

    float4 acc = make_float4(0.f, 0.f, 0.f, 0.f);
    int c = g;
    for (; c + 3 * PGROUPS < total; c += 4 * PGROUPS) {
        const float4 v0 = base[cell_off(c)];
        const float4 v1 = base[cell_off(c + PGROUPS)];
        const float4 v2 = base[cell_off(c + 2 * PGROUPS)];
        const float4 v3 = base[cell_off(c + 3 * PGROUPS)];
        acc.x += (v0.x + v1.x) + (v2.x + v3.x);
        acc.y += (v0.y + v1.y) + (v2.y + v3.y);
        acc.z += (v0.z + v1.z) + (v2.z + v3.z);
        acc.w += (v0.w + v1.w) + (v2.w + v3.w);
    }
    for (; c < total; c += PGROUPS) {
        const float4 v = base[cell_off(c)];
        acc.x += v.x; acc.y += v.y; acc.z += v.z; acc.w += v.w;
    }

    __shared__ float4 part[PGROUPS][DQ_BB];   // 12 KB
    part[g][qd] = acc;
    __syncthreads();

    if (t < DQ_BB) {
        float4 s = part[0][t];
#pragma unroll
        for (int p = 1; p < PGROUPS; ++p) add4(s, part[p][t]);
        s.x *= inv_count; s.y *= inv_count; s.z *= inv_count; s.w *= inv_count;
        ((float4*)pooled)[(size_t)bt * DQ_BB + t] = s;
    }
}

// ---------------- Kernel 2 (v2): GEMM via SGPR A-operands + LDS-free K-loop ----------------
// grid = 256, block = 512 = 8 single-wave K-partitions; lane owns col-quads jq and jq+64.
// Instrumented: K-loop repeated REPEAT times; it>0 passes multiply A by 0 (exact no-op)
// with an opaque runtime-zero address offset to defeat load CSE.
__global__ __launch_bounds__(512) void gemm_ln_kernel(
    const float* __restrict__ pooled,    // [BT,384] means
    const float* __restrict__ bboxes,    // [BT,4] (source of opaque zero)
    const float* __restrict__ W,         // [384,512]
    const float* __restrict__ bias,      // [512]
    const float* __restrict__ gamma,     // [512]
    const float* __restrict__ beta,      // [512]
    const float* __restrict__ mask_tok,  // [512]
    const float* __restrict__ vis,       // [BT]
    float* __restrict__ out)             // [BT,512]
{
    const int tid = threadIdx.x;
    const int p   = tid >> 6;        // partition 0..7 (one wave)
    const int jq  = tid & 63;        // col-quad id; covers jq and jq+64
    const int r0  = blockIdx.x * GROWS;

    __shared__ float4 red4[4][GROWS][CQ];   // 64 KB tree buffer

    // opaque runtime zero (bboxes finite; compiler can't fold x*0.0f)
    const int rz = (int)(bboxes[0] * 0.0f);

    const float4* Wq = (const float4*)W;                  // [384][128] float4
    const float*  A  = pooled + (size_t)r0 * D_BB;        // wave-uniform base

    float4 acc0[GROWS], acc1[GROWS];
#pragma unroll
    for (int r = 0; r < GROWS; ++r) {
        acc0[r] = make_float4(0.f, 0.f, 0.f, 0.f);
        acc1[r] = make_float4(0.f, 0.f, 0.f, 0.f);
    }

    const int dbase = p * GKCHUNK;
#pragma unroll 1
    for (int it = 0; it < REPEAT; ++it) {
        const float msk = (it == 0) ? 1.f : 0.f;
        const int doff = dbase + rz * it;     // rz==0 always; opaque to compiler
#pragma unroll 2
        for (int i = 0; i < GKCHUNK / 4; ++i) {
            const int d = doff + i * 4;
            const float4 w0a = Wq[(size_t)(d + 0) * CQ + jq];
            const float4 w0b = Wq[(size_t)(d + 0) * CQ + jq + 64];
            const float4 w1a = Wq[(size_t)(d + 1) * CQ + jq];
            const float4 w1b = Wq[(size_t)(d + 1) * CQ + jq + 64];
            const float4 w2a = Wq[(size_t)(d + 2) * CQ + jq];
            const float4 w2b = Wq[(size_t)(d + 2) * CQ + jq + 64];
            const float4 w3a = Wq[(size_t)(d + 3) * CQ + jq];
            const float4 w3b = Wq[(size_t)(d + 3) * CQ + jq + 64];
#pragma unroll
            for (int r = 0; r < GROWS; ++r) {
                const float* Ar = A + r * D_BB + d;   // uniform -> s_load
                const float a0 = Ar[0] * msk;
                const float a1 = Ar[1] * msk;
                const float a2 = Ar[2] * msk;
                const float a3 = Ar[3] * msk;
                fma4(acc0[r], a0, w0a); fma4(acc1[r], a0, w0b);
                fma4(acc0[r], a1, w1a); fma4(acc1[r], a1, w1b);
                fma4(acc0[r], a2, w2a); fma4(acc1[r], a2, w2b);
                fma4(acc0[r], a3, w3a); fma4(acc1[r], a3, w3b);
            }
        }
    }

    // ---- cross-partition tree reduction: 8 -> 4 -> 2 -> 1 ----
    if (p >= 4) {
#pragma unroll
        for (int r = 0; r < GROWS; ++r) {
            red4[p - 4][r][jq]      = acc0[r];
            red4[p - 4][r][jq + 64] = acc1[r];
        }
    }
    __syncthreads();
    if (p < 4) {
#pragma unroll
        for (int r = 0; r < GROWS; ++r) {
            add4(acc0[r], red4[p][r][jq]);
            add4(acc1[r], red4[p][r][jq + 64]);
        }
    }
    __syncthreads();
    if (p == 2 || p == 3) {
#pragma unroll
        for (int r = 0; r < GROWS; ++r) {
            red4[p - 2][r][jq]      = acc0[r];
            red4[p - 2][r][jq + 64] = acc1[r];
        }
    }
    __syncthreads();
    if (p < 2) {
#pragma unroll
        for (int r = 0; r < GROWS; ++r) {
            add4(acc0[r], red4[p][r][jq]);
            add4(acc1[r], red4[p][r][jq + 64]);
        }
    }
    __syncthreads();
    if (p == 1) {
#pragma unroll
        for (int r = 0; r < GROWS; ++r) {
            red4[0][r][jq]      = acc0[r];
            red4[0][r][jq + 64] = acc1[r];
        }
    }
    __syncthreads();

    // ---- epilogue: single wave (p==0) holds full 512-col rows ----
    if (p == 0) {
        const float4 bj0 = ((const float4*)bias)[jq];
        const float4 bj1 = ((const float4*)bias)[jq + 64];
        const float4 g0  = ((const float4*)gamma)[jq];
        const float4 g1  = ((const float4*)gamma)[jq + 64];
        const float4 b0  = ((const float4*)beta)[jq];
        const float4 b1  = ((const float4*)beta)[jq + 64];
        const float4 m0  = ((const float4*)mask_tok)[jq];
        const float4 m1  = ((const float4*)mask_tok)[jq + 64];

#pragma unroll
        for (int r = 0; r < GROWS; ++r) {
            add4(acc0[r], red4[0][r][jq]);
            add4(acc1[r], red4[0][r][jq + 64]);
            add4(acc0[r], bj0);
            add4(acc1[r], bj1);

            float s  = acc0[r].x + acc0[r].y + acc0[r].z + acc0[r].w +
                       acc1[r].x + acc1[r].y + acc1[r].z + acc1[r].w;
            float s2 = acc0[r].x * acc0[r].x + acc0[r].y * acc0[r].y +
                       acc0[r].z * acc0[r].z + acc0[r].w * acc0[r].w +
                       acc1[r].x * acc1[r].x + acc1[r].y * acc1[r].y +
                       acc1[r].z * acc1[r].z + acc1[r].w * acc1[r].w;
#pragma unroll
            for (int off = 32; off >= 1; off >>= 1) {
                s  += __shfl_xor(s,  off);
                s2 += __shfl_xor(s2, off);
            }
            const float mean = s * (1.f / (float)D_MODEL);
            const float var  = s2 * (1.f / (float)D_MODEL) - mean * mean;
            const float rstd = rsqrtf(var + LN_EPS);
            const float v    = vis[r0 + r];
            const float iv   = 1.f - v;

            float4 o0, o1;
            o0.x = v * ((acc0[r].x - mean) * rstd * g0.x + b0.x) + iv * m0.x;
            o0.y = v * ((acc0[r].y - mean) * rstd * g0.y + b0.y) + iv * m0.y;
            o0.z = v * ((acc0[r].z - mean) * rstd * g0.z + b0.z) + iv * m0.z;
            o0.w = v * ((acc0[r].w - mean) * rstd * g0.w + b0.w) + iv * m0.w;
            o1.x = v * ((acc1[r].x - mean) * rstd * g1.x + b1.x) + iv * m1.x;
            o1.y = v * ((acc1[r].y - mean) * rstd * g1.y + b1.y) + iv * m1.y;
            o1.z = v * ((acc1[r].z - mean) * rstd * g1.z + b1.z) + iv * m1.z;
            o1.w = v * ((acc1[r].w - mean) * rstd * g1.w + b1.w) + iv * m1.w;
            ((float4*)out)[(size_t)(r0 + r) * CQ + jq]      = o0;
            ((float4*)out)[(size_t)(r0 + r) * CQ + jq + 64] = o1;
        }
    }
}

extern "C" void kernel_launch(void* const* d_in, const int* in_sizes, int n_in,
                              void* d_out, int out_size, void* d_ws, size_t ws_size,
                              hipStream_t stream) {
    const float* patch  = (const float*)d_in[0];  // [2048,196,384]
    const float* bboxes = (const float*)d_in[1];  // [2048,4]
    const float* vis    = (const float*)d_in[2];  // [2048]
    // d_in[3] = B, d_in[4] = T (scalars, unused)
    const float* W      = (const float*)d_in[5];  // [384,512]
    const float* bias   = (const float*)d_in[6];  // [512]
    const float* gamma  = (const float*)d_in[7];  // [512]
    const float* beta   = (const float*)d_in[8];  // [512]
    const float* mtok   = (const float*)d_in[9];  // [1,512]

    float* pooled = (float*)d_ws;                 // [2048,384] means, 3 MB
    float* out    = (float*)d_out;

    pool_kernel<<<BT_TOTAL, 768, 0, stream>>>(patch, bboxes, pooled);
    gemm_ln_kernel<<<BT_TOTAL / GROWS, 512, 0, stream>>>(
        pooled, bboxes, W, bias, gamma, beta, mtok, vis, out);
}

// Round 11
// 36.464 us; speedup vs baseline: 8.0223x; 6.4092x over previous
//
#include <hip/hip_runtime.h>
#include <hip/hip_bf16.h>

#define N_SIDE 14
#define N_PATCH (N_SIDE * N_SIDE)   // 196
#define D_BB 384
#define DQ_BB (D_BB / 4)             // 96 float4 per cell
#define D_MODEL 512
#define CQ (D_MODEL / 4)             // 128 col-quads
#define BT_TOTAL 2048
#define LN_EPS 1e-5f
#define PGROUPS 8                    // pool cell groups (768 threads)

#define GROWS 8                      // rows per gemm block
#define GKP 8                        // K partitions
#define GKCHUNK (D_BB / GKP)         // 48

__device__ __forceinline__ void fma4(float4& a, float s, const float4& wv) {
    a.x = fmaf(s, wv.x, a.x);
    a.y = fmaf(s, wv.y, a.y);
    a.z = fmaf(s, wv.z, a.z);
    a.w = fmaf(s, wv.w, a.w);
}

__device__ __forceinline__ void add4(float4& a, const float4& b) {
    a.x += b.x; a.y += b.y; a.z += b.z; a.w += b.w;
}

__device__ __forceinline__ void box_params(const float* __restrict__ bboxes, int bt,
                                           int& x1, int& y1, int& wd, int& total) {
    const float bx1 = bboxes[bt * 4 + 0];
    const float by1 = bboxes[bt * 4 + 1];
    const float bx2 = bboxes[bt * 4 + 2];
    const float by2 = bboxes[bt * 4 + 3];
    // match reference exactly: clip -> trunc/ceil -> clip -> max
    x1 = (int)fminf(fmaxf(bx1 * (float)N_SIDE, 0.f), (float)(N_SIDE - 1));
    y1 = (int)fminf(fmaxf(by1 * (float)N_SIDE, 0.f), (float)(N_SIDE - 1));
    int x2 = (int)fminf(fmaxf(ceilf(fminf(fmaxf(bx2 * (float)N_SIDE, 0.f), (float)N_SIDE)), 1.f), (float)N_SIDE);
    int y2 = (int)fminf(fmaxf(ceilf(fminf(fmaxf(by2 * (float)N_SIDE, 0.f), (float)N_SIDE)), 1.f), (float)N_SIDE);
    x2 = max(x2, x1 + 1);
    y2 = max(y2, y1 + 1);
    wd = x2 - x1;
    total = wd * (y2 - y1);
}

// ---------------- Kernel 1: ROI mean pool (unchanged: 768 thr, 8 groups, 4-deep) ----------------
__global__ __launch_bounds__(768) void pool_kernel(
    const float* __restrict__ patch,   // [BT,196,384]
    const float* __restrict__ bboxes,  // [BT,4]
    float* __restrict__ pooled)        // [BT,384] means
{
    const int bt = blockIdx.x;
    const int t  = threadIdx.x;
    const int qd = t % DQ_BB;   // channel quad 0..95
    const int g  = t / DQ_BB;   // cell group 0..7

    int x1, y1, wd, total;
    box_params(bboxes, bt, x1, y1, wd, total);
    const float inv_count = 1.f / (float)total;
    const float inv_wd = 1.f / (float)wd;
    const int cell0 = y1 * N_SIDE + x1;

    const float4* __restrict__ base = (const float4*)patch + (size_t)bt * N_PATCH * DQ_BB + qd;

    auto cell_off = [&](int c) -> size_t {
        const int y = (int)(((float)c + 0.5f) * inv_wd);
        const int x = c - y * wd;
        return (size_t)(cell0 + y * N_SIDE + x) * DQ_BB;
    };

    float4 acc = make_float4(0.f, 0.f, 0.f, 0.f);
    int c = g;
    for (; c + 3 * PGROUPS < total; c += 4 * PGROUPS) {
        const float4 v0 = base[cell_off(c)];
        const float4 v1 = base[cell_off(c + PGROUPS)];
        const float4 v2 = base[cell_off(c + 2 * PGROUPS)];
        const float4 v3 = base[cell_off(c + 3 * PGROUPS)];
        acc.x += (v0.x + v1.x) + (v2.x + v3.x);
        acc.y += (v0.y + v1.y) + (v2.y + v3.y);
        acc.z += (v0.z + v1.z) + (v2.z + v3.z);
        acc.w += (v0.w + v1.w) + (v2.w + v3.w);
    }
    for (; c < total; c += PGROUPS) {
        const float4 v = base[cell_off(c)];
        acc.x += v.x; acc.y += v.y; acc.z += v.z; acc.w += v.w;
    }

    __shared__ float4 part[PGROUPS][DQ_BB];   // 12 KB
    part[g][qd] = acc;
    __syncthreads();

    if (t < DQ_BB) {
        float4 s = part[0][t];
#pragma unroll
        for (int p = 1; p < PGROUPS; ++p) add4(s, part[p][t]);
        s.x *= inv_count; s.y *= inv_count; s.z *= inv_count; s.w *= inv_count;
        ((float4*)pooled)[(size_t)bt * DQ_BB + t] = s;
    }
}

// ---------------- Kernel 2 (v3): LDS-free K-loop, 1024 thr = 8 K-parts x 2 col-halves ----------------
// grid = 256 blocks (1/CU, 16 waves/CU = 4/SIMD). Lane owns ONE col-quad.
// W read exactly once per block (201 MB L2 total). A via SGPR s_load.
__global__ __launch_bounds__(1024) void gemm_ln_kernel(
    const float* __restrict__ pooled,    // [BT,384] means
    const float* __restrict__ W,         // [384,512]
    const float* __restrict__ bias,      // [512]
    const float* __restrict__ gamma,     // [512]
    const float* __restrict__ beta,      // [512]
    const float* __restrict__ mask_tok,  // [512]
    const float* __restrict__ vis,       // [BT]
    float* __restrict__ out)             // [BT,512]
{
    const int tid = threadIdx.x;
    const int lq  = tid & 63;        // lane's quad within its col-half
    const int w   = tid >> 6;        // wave 0..15
    const int h   = w & 1;           // col half 0/1
    const int p   = w >> 1;          // K partition 0..7
    const int r0  = blockIdx.x * GROWS;

    __shared__ float4 red4[4][GROWS][CQ];   // 64 KB tree buffer
    __shared__ float  lnred[2][GROWS][2];

    const int hq = h * 64 + lq;      // global col quad 0..127
    // wave-uniform K base, forced into SGPR so A loads become s_load
    const int dbase = __builtin_amdgcn_readfirstlane(p * GKCHUNK);

    const float4* Wq = (const float4*)W;              // [384][128] float4
    const float*  A  = pooled + (size_t)r0 * D_BB;    // wave-uniform base

    float4 acc[GROWS];
#pragma unroll
    for (int r = 0; r < GROWS; ++r) acc[r] = make_float4(0.f, 0.f, 0.f, 0.f);

#pragma unroll 2
    for (int i = 0; i < GKCHUNK / 4; ++i) {
        const int d = dbase + i * 4;
        const float4 w0 = Wq[(size_t)(d + 0) * CQ + hq];
        const float4 w1 = Wq[(size_t)(d + 1) * CQ + hq];
        const float4 w2 = Wq[(size_t)(d + 2) * CQ + hq];
        const float4 w3 = Wq[(size_t)(d + 3) * CQ + hq];
#pragma unroll
        for (int r = 0; r < GROWS; ++r) {
            const float* Ar = A + r * D_BB + d;   // uniform -> s_load_dwordx4
            const float a0 = Ar[0];
            const float a1 = Ar[1];
            const float a2 = Ar[2];
            const float a3 = Ar[3];
            fma4(acc[r], a0, w0);
            fma4(acc[r], a1, w1);
            fma4(acc[r], a2, w2);
            fma4(acc[r], a3, w3);
        }
    }

    // ---- cross-partition tree reduction per col-half: 8 -> 4 -> 2 -> 1 ----
    if (p >= 4) {
#pragma unroll
        for (int r = 0; r < GROWS; ++r) red4[p - 4][r][hq] = acc[r];
    }
    __syncthreads();
    if (p < 4) {
#pragma unroll
        for (int r = 0; r < GROWS; ++r) add4(acc[r], red4[p][r][hq]);
    }
    __syncthreads();
    if (p == 2 || p == 3) {
#pragma unroll
        for (int r = 0; r < GROWS; ++r) red4[p - 2][r][hq] = acc[r];
    }
    __syncthreads();
    if (p < 2) {
#pragma unroll
        for (int r = 0; r < GROWS; ++r) add4(acc[r], red4[p][r][hq]);
    }
    __syncthreads();
    if (p == 1) {
#pragma unroll
        for (int r = 0; r < GROWS; ++r) red4[0][r][hq] = acc[r];
    }
    __syncthreads();

    // ---- epilogue: waves (p==0, h=0/1) hold full-K sums for their 256 cols ----
    if (p == 0) {
        const float4 bj = ((const float4*)bias)[hq];
#pragma unroll
        for (int r = 0; r < GROWS; ++r) {
            add4(acc[r], red4[0][r][hq]);
            add4(acc[r], bj);
            float s  = acc[r].x + acc[r].y + acc[r].z + acc[r].w;
            float s2 = acc[r].x * acc[r].x + acc[r].y * acc[r].y +
                       acc[r].z * acc[r].z + acc[r].w * acc[r].w;
#pragma unroll
            for (int off = 32; off >= 1; off >>= 1) {
                s  += __shfl_xor(s,  off);
                s2 += __shfl_xor(s2, off);
            }
            if (lq == 0) { lnred[h][r][0] = s; lnred[h][r][1] = s2; }
        }
    }
    __syncthreads();

    if (p == 0) {
        const float4 g4 = ((const float4*)gamma)[hq];
        const float4 b4 = ((const float4*)beta)[hq];
        const float4 m4 = ((const float4*)mask_tok)[hq];
#pragma unroll
        for (int r = 0; r < GROWS; ++r) {
            const float s    = lnred[0][r][0] + lnred[1][r][0];
            const float s2   = lnred[0][r][1] + lnred[1][r][1];
            const float mean = s * (1.f / (float)D_MODEL);
            const float var  = s2 * (1.f / (float)D_MODEL) - mean * mean;
            const float rstd = rsqrtf(var + LN_EPS);
            const float v    = vis[r0 + r];
            const float iv   = 1.f - v;
            float4 o;
            o.x = v * ((acc[r].x - mean) * rstd * g4.x + b4.x) + iv * m4.x;
            o.y = v * ((acc[r].y - mean) * rstd * g4.y + b4.y) + iv * m4.y;
            o.z = v * ((acc[r].z - mean) * rstd * g4.z + b4.z) + iv * m4.z;
            o.w = v * ((acc[r].w - mean) * rstd * g4.w + b4.w) + iv * m4.w;
            ((float4*)out)[(size_t)(r0 + r) * CQ + hq] = o;
        }
    }
}

extern "C" void kernel_launch(void* const* d_in, const int* in_sizes, int n_in,
                              void* d_out, int out_size, void* d_ws, size_t ws_size,
                              hipStream_t stream) {
    const float* patch  = (const float*)d_in[0];  // [2048,196,384]
    const float* bboxes = (const float*)d_in[1];  // [2048,4]
    const float* vis    = (const float*)d_in[2];  // [2048]
    // d_in[3] = B, d_in[4] = T (scalars, unused)
    const float* W      = (const float*)d_in[5];  // [384,512]
    const float* bias   = (const float*)d_in[6];  // [512]
    const float* gamma  = (const float*)d_in[7];  // [512]
    const float* beta   = (const float*)d_in[8];  // [512]
    const float* mtok   = (const float*)d_in[9];  // [1,512]

    float* pooled = (float*)d_ws;                 // [2048,384] means, 3 MB
    float* out    = (float*)d_out;

    pool_kernel<<<BT_TOTAL, 768, 0, stream>>>(patch, bboxes, pooled);
    gemm_ln_kernel<<<BT_TOTAL / GROWS, 1024, 0, stream>>>(
        pooled, W, bias, gamma, beta, mtok, vis, out);
}